// Round 3
// baseline (212.306 us; speedup 1.0000x reference)
//
#include <hip/hip_runtime.h>
#include <hip/hip_cooperative_groups.h>

namespace cg = cooperative_groups;

// GaussianAttention: S=512, B=32, T=1024, E=512, Q=128. f32 in / f32 out.
// out = [ new_context (S*B*E) | mean (S*B) ].
//
// R9: SINGLE cooperative dispatch. Phase 1 = old K0 (each block computes the
//   16 dot-pairs for its own s-chunk; wave-per-(s,b), bit-identical shfl_down
//   tree + expf so numerics match R8 exactly). grid.sync() (grid is fully
//   co-resident: 1024 blocks x 4 waves = 16/32 waves/CU, <=128 VGPR forced by
//   __launch_bounds__(256,4)). Phase 2 = R8's fused scan + ctx.
//
// NOTE (R6 post-mortem): do NOT serialize K0 as block-per-b — 32 blocks =
//   2.5% occupancy, latency-bound. This fusion keeps full grid parallelism.
// NOTE (R7 post-mortem): K2 occupancy 2->4 waves/SIMD + prefetch = only
//   -1.5 us => kernels are a minority of dur_us; harness poison fills
//   (256 MiB @ ~41 us each, 81% HBM peak) dominate the timed region.
// NOTE (R8 post-mortem): removing K1's dispatch saved 3.8 us (~= K1 + gap),
//   confirming launch/gap overhead ~2 us per dispatch. This round removes
//   the last one.

#define S_DIM 512
#define B_DIM 32
#define T_DIM 1024
#define E_DIM 512
#define Q_DIM 128
#define WIN_CUT 20.0f
#define CH 16     // s-values per block
#define TSEG 64   // t-segment (union window is ~14-40 rows, 64 covers it)

typedef float v4f __attribute__((ext_vector_type(4)));

__global__ __launch_bounds__(256, 4) void fused_kernel(
    const float* __restrict__ query,    // [S,B,Q]
    const float* __restrict__ W,        // [2,Q]
    const float* __restrict__ bias,     // [2]
    const float* __restrict__ emb,      // [T,B,E]
    const float* __restrict__ mask,     // [T,B]
    const float* __restrict__ position, // [S,B]
    float* __restrict__ ws_mraw,        // [B,S]
    float* __restrict__ ws_std,         // [B,S]
    float* __restrict__ out,            // [S,B,E]
    float* __restrict__ out_mean)       // [S,B]
{
    __shared__ float lds_w[TSEG * CH];
    __shared__ float lds_mean[CH], lds_std[CH];
    __shared__ float lds_lo[CH], lds_hi[CH];
    __shared__ float lds_wt[4];
    __shared__ int s_tlo, s_thi;
    const int c = blockIdx.x, b = blockIdx.y;
    const int s0 = c * CH;
    const int tid = threadIdx.x;
    const int wv = tid >> 6, lane = tid & 63;
    const int half = tid >> 7;       // 0: rows s0..s0+7, 1: rows s0+8..s0+15
    const int htid = tid & 127;      // E/4 lane within half

    // ---- phase 1 (was K0): dots for s in [s0, s0+16), batch b.
    // Wave wv handles s = s0 + wv*4 + k, k=0..3 — identical lane layout,
    // reduction tree and expf as the standalone dot_kernel (numerics match).
    {
        float2 qv[4];
        #pragma unroll
        for (int k = 0; k < 4; ++k) {
            const int s = s0 + wv * 4 + k;
            qv[k] = ((const float2*)(query + ((size_t)s * B_DIM + b) * Q_DIM))[lane];
        }
        const float w0a = W[2 * lane],         w0b = W[2 * lane + 1];
        const float w1a = W[Q_DIM + 2 * lane], w1b = W[Q_DIM + 2 * lane + 1];
        const float b0 = bias[0], b1 = bias[1];
        #pragma unroll
        for (int k = 0; k < 4; ++k) {
            float d0 = qv[k].x * w0a + qv[k].y * w0b;
            float d1 = qv[k].x * w1a + qv[k].y * w1b;
            #pragma unroll
            for (int off = 32; off; off >>= 1) {
                d0 += __shfl_down(d0, off);
                d1 += __shfl_down(d1, off);
            }
            if (lane == 0) {
                const int s = s0 + wv * 4 + k;
                ws_mraw[(size_t)b * S_DIM + s] = expf(d0 + b0);
                ws_std[(size_t)b * S_DIM + s]  = expf(d1 + b1);
            }
        }
    }
    cg::this_grid().sync();   // device-scope fence: ws visible across XCDs

    // ---- phase 2a: inclusive cumsum of mraw[b, 0..511] (block-local scan) ----
    float2 f2 = ((const float2*)(ws_mraw + (size_t)b * S_DIM))[tid];
    float sc = f2.x + f2.y;
    #pragma unroll
    for (int off = 1; off < 64; off <<= 1) {
        float u = __shfl_up(sc, off);
        if (lane >= off) sc += u;
    }
    if (lane == 63) lds_wt[wv] = sc;
    __syncthreads();
    float woff = 0.f;
    #pragma unroll
    for (int w = 0; w < 4; ++w) woff += (w < wv) ? lds_wt[w] : 0.f;
    if (tid >= (s0 >> 1) && tid < ((s0 + CH) >> 1)) {
        const int i0 = tid * 2 - s0;              // 0,2,..,14
        const int sa = s0 + i0, sb = sa + 1;
        float m0 = position[(size_t)sa * B_DIM + b] + (woff + sc - f2.y) * 0.05f;
        float m1 = position[(size_t)sb * B_DIM + b] + (woff + sc) * 0.05f;
        float sd0 = ws_std[(size_t)b * S_DIM + sa];
        float sd1 = ws_std[(size_t)b * S_DIM + sb];
        lds_mean[i0] = m0;  lds_mean[i0 + 1] = m1;
        lds_std[i0]  = sd0; lds_std[i0 + 1]  = sd1;
        float r0 = __fsqrt_rn(WIN_CUT / sd0);
        float r1 = __fsqrt_rn(WIN_CUT / sd1);
        lds_lo[i0] = m0 - r0; lds_hi[i0] = m0 + r0;
        lds_lo[i0 + 1] = m1 - r1; lds_hi[i0 + 1] = m1 + r1;
        out_mean[(size_t)sa * B_DIM + b] = m0;
        out_mean[(size_t)sb * B_DIM + b] = m1;
    }
    __syncthreads();
    if (tid == 0) {
        float lo = 1e30f, hi = -1e30f;
        #pragma unroll
        for (int i = 0; i < CH; ++i) {
            lo = fminf(lo, lds_lo[i]);
            hi = fmaxf(hi, lds_hi[i]);
        }
        int tlo = (int)floorf(lo);
        if (tlo < 0) tlo = 0; if (tlo > T_DIM - 1) tlo = T_DIM - 1;
        int thi = (int)ceilf(hi);
        if (thi > T_DIM - 1) thi = T_DIM - 1; if (thi < tlo) thi = tlo;
        s_tlo = tlo; s_thi = thi;
    }
    __syncthreads();
    const int tlo = s_tlo, thi = s_thi;

    // ---- phase 2b: windowed context accumulation ----
    v4f acc[8];
    #pragma unroll
    for (int i = 0; i < 8; ++i) acc[i] = (v4f)0.f;

    for (int tseg = tlo; tseg <= thi; tseg += TSEG) {
        // Weights: all 256 threads; thread covers toff = tid>>2, 4 i-slots.
        {
            const int toff = tid >> 2;
            const int ibase = (tid & 3) * 4;
            const int t = tseg + toff;
            float mv = 0.f;
            if (t <= thi) mv = mask[(size_t)t * B_DIM + b];
            v4f w;
            #pragma unroll
            for (int j = 0; j < 4; ++j) {
                int i = ibase + j;
                float d = lds_mean[i] - (float)t;
                w[j] = (t <= thi) ? __expf(-lds_std[i] * d * d) * mv : 0.f;
            }
            *(v4f*)(lds_w + toff * CH + ibase) = w;
        }
        __syncthreads();
        const int tend = (thi < tseg + TSEG - 1) ? thi : (tseg + TSEG - 1);
        const float* wbase = lds_w + half * 8;
        v4f v = ((const v4f*)(emb + ((size_t)tseg * B_DIM + b) * E_DIM))[htid];
        for (int t = tseg; t <= tend; ++t) {
            // 1-deep prefetch: next row load issues before this row's FMAs.
            const int tn = (t < tend) ? t + 1 : t;
            v4f vn = ((const v4f*)(emb + ((size_t)tn * B_DIM + b) * E_DIM))[htid];
            const float* wrow = wbase + (t - tseg) * CH;
            #pragma unroll
            for (int i = 0; i < 8; ++i) {
                float w = wrow[i];
                acc[i] += w * v;
            }
            v = vn;
        }
        __syncthreads();
    }
    #pragma unroll
    for (int i = 0; i < 8; ++i) {
        v4f* dst = (v4f*)(out + ((size_t)(s0 + half * 8 + i) * B_DIM + b) * E_DIM);
        __builtin_nontemporal_store(acc[i], dst + htid);  // write-once, bypass L2
    }
}

extern "C" void kernel_launch(void* const* d_in, const int* in_sizes, int n_in,
                              void* d_out, int out_size, void* d_ws, size_t ws_size,
                              hipStream_t stream) {
    const float* query = (const float*)d_in[0]; // [S,B,Q]
    const float* emb   = (const float*)d_in[1]; // [T,B,E]
    const float* mask  = (const float*)d_in[2]; // [T,B]
    const float* pos   = (const float*)d_in[3]; // [S,B]
    const float* W     = (const float*)d_in[4]; // [2,Q]
    const float* bias  = (const float*)d_in[5]; // [2]

    float* out_ctx  = (float*)d_out;                            // S*B*E
    float* out_mean = out_ctx + (size_t)S_DIM * B_DIM * E_DIM;  // S*B

    float* ws_mraw = (float*)d_ws;                      // [B,S]
    float* ws_std  = ws_mraw + (size_t)S_DIM * B_DIM;   // [B,S] (128 KiB total)

    void* args[] = {
        (void*)&query, (void*)&W, (void*)&bias, (void*)&emb, (void*)&mask,
        (void*)&pos, (void*)&ws_mraw, (void*)&ws_std, (void*)&out_ctx,
        (void*)&out_mean
    };
    hipLaunchCooperativeKernel((const void*)fused_kernel,
                               dim3(S_DIM / CH, B_DIM), dim3(256, 1, 1),
                               args, 0, stream);
}

// Round 4
// 124.964 us; speedup vs baseline: 1.6989x; 1.6989x over previous
//
#include <hip/hip_runtime.h>
#include <hip/hip_bf16.h>

// GaussianAttention: S=512, B=32, T=1024, E=512, Q=128. f32 in / f32 out.
// out = [ new_context (S*B*E) | mean (S*B) ].
//
// R10: revert R9's cooperative fusion (grid.sync() cost ~87 us on this
//   runtime: fused_kernel measured 97.2 us with VALUBusy 4.8% ~= 4.7 us of
//   real work — the barrier IS the stall). Back to R8's two dispatches:
//   K0 (dots) -> K2 (fused scan + windowed context).
//   Decomposition pinned by R9: fixed harness region ~113 us (2x 256-MiB
//   poison fills @41.5 + restores); our kernels+gap ~12 us vs ~9 us
//   mandatory-traffic floor.
// R10 deltas vs R8 (numerics-identical):
//   - K0: 2 pairs/wave (2048 blocks, 8 waves/SIMD = 1 round, 2x MLP).
//   - K2: t-loop prefetch depth 2 (covers L2/HBM latency at ramp).
//
// NOTE (R6): do NOT serialize K0 as block-per-b — 32 blocks latency-bound.
// NOTE (R7): K2 occupancy 2->4 waves/SIMD + prefetch = only -1.5 us.
// NOTE (R8): removing K1's dispatch saved 3.8 us (~= K1 + 2 us gap).
// NOTE (R9): hipLaunchCooperativeKernel + grid.sync() = +87 us. Never again.

#define S_DIM 512
#define B_DIM 32
#define T_DIM 1024
#define E_DIM 512
#define Q_DIM 128
#define WIN_CUT 20.0f
#define CH 16     // s-values per K2 block
#define TSEG 64   // t-segment (union window is ~14-40 rows, 64 covers it)

typedef float v4f __attribute__((ext_vector_type(4)));

// K0: 4 waves/block, TWO (s,b) pairs per wave. grid = S*B/8 = 2048.
__global__ __launch_bounds__(256) void dot_kernel(
    const float* __restrict__ query,  // [S,B,Q]
    const float* __restrict__ W,      // [2,Q]
    const float* __restrict__ bias,   // [2]
    float* __restrict__ ws_mraw,      // [B,S]
    float* __restrict__ ws_std)       // [B,S]
{
    const int wave = threadIdx.x >> 6;
    const int lane = threadIdx.x & 63;
    const int pair0 = (blockIdx.x * 4 + wave) * 2;   // = s*B + b
    const float2 va = ((const float2*)(query + (size_t)pair0 * Q_DIM))[lane];
    const float2 vb = ((const float2*)(query + (size_t)(pair0 + 1) * Q_DIM))[lane];
    const float w0a = W[2 * lane],         w0b = W[2 * lane + 1];
    const float w1a = W[Q_DIM + 2 * lane], w1b = W[Q_DIM + 2 * lane + 1];
    // Per-pair expressions + shfl tree identical to the R8 kernel -> numerics match.
    float a0 = va.x * w0a + va.y * w0b;
    float a1 = va.x * w1a + va.y * w1b;
    float c0 = vb.x * w0a + vb.y * w0b;
    float c1 = vb.x * w1a + vb.y * w1b;
    #pragma unroll
    for (int off = 32; off; off >>= 1) {
        a0 += __shfl_down(a0, off);
        a1 += __shfl_down(a1, off);
        c0 += __shfl_down(c0, off);
        c1 += __shfl_down(c1, off);
    }
    if (lane == 0) {
        const float b0 = bias[0], b1 = bias[1];
        int s = pair0 / B_DIM, b = pair0 % B_DIM;
        ws_mraw[(size_t)b * S_DIM + s] = expf(a0 + b0);
        ws_std[(size_t)b * S_DIM + s]  = expf(a1 + b1);
        int s2 = (pair0 + 1) / B_DIM, b2 = (pair0 + 1) % B_DIM;
        ws_mraw[(size_t)b2 * S_DIM + s2] = expf(c0 + b0);
        ws_std[(size_t)b2 * S_DIM + s2]  = expf(c1 + b1);
    }
}

// K2: grid (S/CH, B), 256 threads. Scan fused; two s-halves share emb rows.
__global__ __launch_bounds__(256) void ctx_kernel(
    const float* __restrict__ emb,      // [T,B,E]
    const float* __restrict__ mask,     // [T,B]
    const float* __restrict__ ws_mraw,  // [B,S]
    const float* __restrict__ ws_std,   // [B,S]
    const float* __restrict__ position, // [S,B]
    float* __restrict__ out,            // [S,B,E]
    float* __restrict__ out_mean)       // [S,B]
{
    __shared__ float lds_w[TSEG * CH];
    __shared__ float lds_mean[CH], lds_std[CH];
    __shared__ float lds_lo[CH], lds_hi[CH];
    __shared__ float lds_wt[4];
    __shared__ int s_tlo, s_thi;
    const int c = blockIdx.x, b = blockIdx.y;
    const int s0 = c * CH;
    const int tid = threadIdx.x;
    const int wv = tid >> 6, lane = tid & 63;
    const int half = tid >> 7;       // 0: rows s0..s0+7, 1: rows s0+8..s0+15
    const int htid = tid & 127;      // E/4 lane within half

    // ---- fused scan: inclusive cumsum of mraw[b, 0..511] ----
    float2 f2 = ((const float2*)(ws_mraw + (size_t)b * S_DIM))[tid];
    float sc = f2.x + f2.y;
    #pragma unroll
    for (int off = 1; off < 64; off <<= 1) {
        float u = __shfl_up(sc, off);
        if (lane >= off) sc += u;
    }
    if (lane == 63) lds_wt[wv] = sc;
    __syncthreads();
    float woff = 0.f;
    #pragma unroll
    for (int w = 0; w < 4; ++w) woff += (w < wv) ? lds_wt[w] : 0.f;
    if (tid >= (s0 >> 1) && tid < ((s0 + CH) >> 1)) {
        const int i0 = tid * 2 - s0;              // 0,2,..,14
        const int sa = s0 + i0, sb = sa + 1;
        float m0 = position[(size_t)sa * B_DIM + b] + (woff + sc - f2.y) * 0.05f;
        float m1 = position[(size_t)sb * B_DIM + b] + (woff + sc) * 0.05f;
        float sd0 = ws_std[(size_t)b * S_DIM + sa];
        float sd1 = ws_std[(size_t)b * S_DIM + sb];
        lds_mean[i0] = m0;  lds_mean[i0 + 1] = m1;
        lds_std[i0]  = sd0; lds_std[i0 + 1]  = sd1;
        float r0 = __fsqrt_rn(WIN_CUT / sd0);
        float r1 = __fsqrt_rn(WIN_CUT / sd1);
        lds_lo[i0] = m0 - r0; lds_hi[i0] = m0 + r0;
        lds_lo[i0 + 1] = m1 - r1; lds_hi[i0 + 1] = m1 + r1;
        out_mean[(size_t)sa * B_DIM + b] = m0;
        out_mean[(size_t)sb * B_DIM + b] = m1;
    }
    __syncthreads();
    if (tid == 0) {
        float lo = 1e30f, hi = -1e30f;
        #pragma unroll
        for (int i = 0; i < CH; ++i) {
            lo = fminf(lo, lds_lo[i]);
            hi = fmaxf(hi, lds_hi[i]);
        }
        int tlo = (int)floorf(lo);
        if (tlo < 0) tlo = 0; if (tlo > T_DIM - 1) tlo = T_DIM - 1;
        int thi = (int)ceilf(hi);
        if (thi > T_DIM - 1) thi = T_DIM - 1; if (thi < tlo) thi = tlo;
        s_tlo = tlo; s_thi = thi;
    }
    __syncthreads();
    const int tlo = s_tlo, thi = s_thi;

    v4f acc[8];
    #pragma unroll
    for (int i = 0; i < 8; ++i) acc[i] = (v4f)0.f;

    for (int tseg = tlo; tseg <= thi; tseg += TSEG) {
        // Weights: all 256 threads; thread covers toff = tid>>2, 4 i-slots.
        {
            const int toff = tid >> 2;
            const int ibase = (tid & 3) * 4;
            const int t = tseg + toff;
            float mv = 0.f;
            if (t <= thi) mv = mask[(size_t)t * B_DIM + b];
            v4f w;
            #pragma unroll
            for (int j = 0; j < 4; ++j) {
                int i = ibase + j;
                float d = lds_mean[i] - (float)t;
                w[j] = (t <= thi) ? __expf(-lds_std[i] * d * d) * mv : 0.f;
            }
            *(v4f*)(lds_w + toff * CH + ibase) = w;
        }
        __syncthreads();
        const int tend = (thi < tseg + TSEG - 1) ? thi : (tseg + TSEG - 1);
        const float* wbase = lds_w + half * 8;
        // Depth-2 prefetch pipeline over emb rows.
        v4f v0 = ((const v4f*)(emb + ((size_t)tseg * B_DIM + b) * E_DIM))[htid];
        const int t1 = (tseg + 1 <= tend) ? tseg + 1 : tend;
        v4f v1 = ((const v4f*)(emb + ((size_t)t1 * B_DIM + b) * E_DIM))[htid];
        for (int t = tseg; t <= tend; ++t) {
            const int tn = (t + 2 <= tend) ? t + 2 : tend;
            v4f vn = ((const v4f*)(emb + ((size_t)tn * B_DIM + b) * E_DIM))[htid];
            const float* wrow = wbase + (t - tseg) * CH;
            #pragma unroll
            for (int i = 0; i < 8; ++i) {
                float w = wrow[i];
                acc[i] += w * v0;
            }
            v0 = v1; v1 = vn;
        }
        __syncthreads();
    }
    #pragma unroll
    for (int i = 0; i < 8; ++i) {
        v4f* dst = (v4f*)(out + ((size_t)(s0 + half * 8 + i) * B_DIM + b) * E_DIM);
        __builtin_nontemporal_store(acc[i], dst + htid);  // write-once, bypass L2
    }
}

extern "C" void kernel_launch(void* const* d_in, const int* in_sizes, int n_in,
                              void* d_out, int out_size, void* d_ws, size_t ws_size,
                              hipStream_t stream) {
    const float* query = (const float*)d_in[0]; // [S,B,Q]
    const float* emb   = (const float*)d_in[1]; // [T,B,E]
    const float* mask  = (const float*)d_in[2]; // [T,B]
    const float* pos   = (const float*)d_in[3]; // [S,B]
    const float* W     = (const float*)d_in[4]; // [2,Q]
    const float* bias  = (const float*)d_in[5]; // [2]

    float* out_ctx  = (float*)d_out;                            // S*B*E
    float* out_mean = out_ctx + (size_t)S_DIM * B_DIM * E_DIM;  // S*B

    float* ws_mraw = (float*)d_ws;                      // [B,S]
    float* ws_std  = ws_mraw + (size_t)S_DIM * B_DIM;   // [B,S] (128 KiB total)

    dot_kernel<<<(S_DIM * B_DIM) / 8, 256, 0, stream>>>(query, W, bias, ws_mraw, ws_std);
    ctx_kernel<<<dim3(S_DIM / CH, B_DIM), 256, 0, stream>>>(
        emb, mask, ws_mraw, ws_std, pos, out_ctx, out_mean);
}